// Round 2
// baseline (152.796 us; speedup 1.0000x reference)
//
#include <hip/hip_runtime.h>

#define CC 256
#define EE 128
#define BB 8
#define NN 3136
#define NN4 784      // NN / 4 (float4 per row)
#define T4 16        // float4 per i-tile (64 spatial positions)
#define NTILES 49    // NN4 / T4

__device__ __forceinline__ float waveReduceSum(float v) {
    #pragma unroll
    for (int off = 32; off > 0; off >>= 1) v += __shfl_down(v, off, 64);
    return v;
}

// xbar[b*C+c] = mean_i x[b,c,i]
__global__ void k_xbar(const float* __restrict__ x, float* __restrict__ xbar) {
    int row = blockIdx.x;          // b*C + c
    int tid = threadIdx.x;
    const float4* xr = (const float4*)(x + (size_t)row * NN);
    float acc = 0.f;
    for (int i = tid; i < NN4; i += 256) {
        float4 v = xr[i];
        acc += (v.x + v.y) + (v.z + v.w);
    }
    acc = waveReduceSum(acc);
    __shared__ float red[4];
    int wid = tid >> 6, lane = tid & 63;
    if (lane == 0) red[wid] = acc;
    __syncthreads();
    if (tid == 0) xbar[row] = (red[0] + red[1] + red[2] + red[3]) * (1.0f / NN);
}

// per-b (wave-per-row, coalesced):
//   vbar = Wv@xbar + bv ;  gexp[b,c] = Wexp[c,:]@vbar   (NO bexp here)
// block 0 also: A[c] = sum_e Wcat[e]*Wq[e,c] + Wcat[E+e]*Wk[e,c]
//               cst  = sum_e Wcat[e]*bq[e]   + Wcat[E+e]*bk[e]
__global__ void k_small(const float* __restrict__ xbar,
                        const float* __restrict__ Wq, const float* __restrict__ bq,
                        const float* __restrict__ Wk, const float* __restrict__ bk,
                        const float* __restrict__ Wv, const float* __restrict__ bv,
                        const float* __restrict__ Wcat,
                        const float* __restrict__ Wexp,
                        float* __restrict__ gexp, float* __restrict__ Aout,
                        float* __restrict__ cst) {
    int b = blockIdx.x, tid = threadIdx.x;
    int w = tid >> 6, lane = tid & 63;
    __shared__ float xb_s[CC];
    __shared__ float vb_s[EE];
    xb_s[tid] = xbar[b * CC + tid];
    __syncthreads();
    // vbar: 128 rows, 32 per wave; each row = coalesced 256-float dot
    for (int r = 0; r < 32; r++) {
        int e = w * 32 + r;
        const float* wr = Wv + e * CC;
        float acc = wr[lane]        * xb_s[lane]
                  + wr[64 + lane]   * xb_s[64 + lane]
                  + wr[128 + lane]  * xb_s[128 + lane]
                  + wr[192 + lane]  * xb_s[192 + lane];
        acc = waveReduceSum(acc);
        if (lane == 0) vb_s[e] = acc + bv[e];
    }
    __syncthreads();
    // gexp: 256 rows, 64 per wave; each row = coalesced 128-float dot
    for (int r = 0; r < 64; r++) {
        int c = w * 64 + r;
        const float* we = Wexp + c * EE;
        float acc = we[lane] * vb_s[lane] + we[64 + lane] * vb_s[64 + lane];
        acc = waveReduceSum(acc);
        if (lane == 0) gexp[b * CC + c] = acc;
    }
    if (b == 0) {
        // A: thread-per-column, loads coalesced across lanes
        float a = 0.f;
        #pragma unroll 8
        for (int e = 0; e < EE; e++)
            a += Wcat[e] * Wq[e * CC + tid] + Wcat[EE + e] * Wk[e * CC + tid];
        Aout[tid] = a;
        if (tid < 64) {
            float cp = Wcat[tid] * bq[tid] + Wcat[tid + 64] * bq[tid + 64]
                     + Wcat[EE + tid] * bk[tid] + Wcat[EE + tid + 64] * bk[tid + 64];
            cp = waveReduceSum(cp);
            if (tid == 0) cst[0] = cp;
        }
    }
}

// fused s + out. block = (b, tile of 16 float4 = 64 spatial positions)
// phase A: s[i] = relu(sum_c A[c]*x[b,c,i] + cst)
// phase B: out[b,c,i] = x[b,c,i] + s[i]*gexp[b,c] + bexp[c]
__global__ void __launch_bounds__(256) k_fused(
        const float* __restrict__ x, const float* __restrict__ A,
        const float* __restrict__ cst, const float* __restrict__ gexp,
        const float* __restrict__ bexp, float* __restrict__ out) {
    int b = blockIdx.x / NTILES;
    int tile = blockIdx.x - b * NTILES;
    int tid = threadIdx.x;
    int i4l = tid & 15, cg = tid >> 4;   // 16 i-slots x 16 c-groups

    __shared__ float A_s[CC];
    __shared__ float g_s[CC];
    __shared__ float be_s[CC];
    __shared__ float4 part[16][16];
    __shared__ float4 s_s[16];

    A_s[tid]  = A[tid];
    g_s[tid]  = gexp[b * CC + tid];
    be_s[tid] = bexp[tid];
    __syncthreads();

    const float4* x4 = (const float4*)x + (size_t)b * CC * NN4 + tile * T4;
    float4*       o4 = (float4*)out     + (size_t)b * CC * NN4 + tile * T4;

    // phase A: partial c-sum over this thread's 16 channels
    float4 acc = make_float4(0.f, 0.f, 0.f, 0.f);
    #pragma unroll
    for (int j = 0; j < 16; j++) {
        int c = cg * 16 + j;
        float a = A_s[c];
        float4 v = x4[(size_t)c * NN4 + i4l];
        acc.x = fmaf(a, v.x, acc.x);
        acc.y = fmaf(a, v.y, acc.y);
        acc.z = fmaf(a, v.z, acc.z);
        acc.w = fmaf(a, v.w, acc.w);
    }
    part[cg][i4l] = acc;
    __syncthreads();
    if (tid < 16) {
        float4 sum = part[0][tid];
        #pragma unroll
        for (int g = 1; g < 16; g++) {
            float4 p = part[g][tid];
            sum.x += p.x; sum.y += p.y; sum.z += p.z; sum.w += p.w;
        }
        float cv = cst[0];
        float4 s;
        s.x = fmaxf(sum.x + cv, 0.f);
        s.y = fmaxf(sum.y + cv, 0.f);
        s.z = fmaxf(sum.z + cv, 0.f);
        s.w = fmaxf(sum.w + cv, 0.f);
        s_s[tid] = s;
    }
    __syncthreads();

    // phase B: stream all 256 channels of this i-tile (x re-read hits L2)
    float4 sv = s_s[i4l];
    #pragma unroll
    for (int j = 0; j < 16; j++) {
        int c = j * 16 + cg;
        float g  = g_s[c];
        float be = be_s[c];
        size_t off = (size_t)c * NN4 + i4l;
        float4 xv = x4[off];
        float4 o;
        o.x = fmaf(sv.x, g, xv.x) + be;
        o.y = fmaf(sv.y, g, xv.y) + be;
        o.z = fmaf(sv.z, g, xv.z) + be;
        o.w = fmaf(sv.w, g, xv.w) + be;
        o4[off] = o;
    }
}

extern "C" void kernel_launch(void* const* d_in, const int* in_sizes, int n_in,
                              void* d_out, int out_size, void* d_ws, size_t ws_size,
                              hipStream_t stream) {
    const float* x    = (const float*)d_in[0];
    const float* Wq   = (const float*)d_in[1];
    const float* bq   = (const float*)d_in[2];
    const float* Wk   = (const float*)d_in[3];
    const float* bk   = (const float*)d_in[4];
    const float* Wv   = (const float*)d_in[5];
    const float* bv   = (const float*)d_in[6];
    const float* Wcat = (const float*)d_in[7];
    const float* Wexp = (const float*)d_in[8];
    const float* bexp = (const float*)d_in[9];
    float* out = (float*)d_out;

    float* ws   = (float*)d_ws;
    float* xbar = ws;                 // 2048
    float* gexp = ws + 2048;          // 2048
    float* A    = ws + 4096;          // 256
    float* cst  = ws + 4352;          // 1

    k_xbar<<<BB * CC, 256, 0, stream>>>(x, xbar);
    k_small<<<BB, 256, 0, stream>>>(xbar, Wq, bq, Wk, bk, Wv, bv, Wcat, Wexp,
                                    gexp, A, cst);
    k_fused<<<BB * NTILES, 256, 0, stream>>>(x, A, cst, gexp, bexp, out);
}

// Round 3
// 113.457 us; speedup vs baseline: 1.3467x; 1.3467x over previous
//
#include <hip/hip_runtime.h>

#define CC 256
#define EE 128
#define BB 8
#define NN 3136
#define NN4 784      // NN / 4 (float4 per row)
#define T4 16        // float4 per i-tile (64 spatial positions)
#define NTILES 49    // NN4 / T4

__device__ __forceinline__ float waveReduceSum(float v) {
    #pragma unroll
    for (int off = 32; off > 0; off >>= 1) v += __shfl_down(v, off, 64);
    return v;
}

// xbar[b*C+c] = mean_i x[b,c,i]
__global__ void k_xbar(const float* __restrict__ x, float* __restrict__ xbar) {
    int row = blockIdx.x;          // b*C + c
    int tid = threadIdx.x;
    const float4* xr = (const float4*)(x + (size_t)row * NN);
    float acc = 0.f;
    for (int i = tid; i < NN4; i += 256) {
        float4 v = xr[i];
        acc += (v.x + v.y) + (v.z + v.w);
    }
    acc = waveReduceSum(acc);
    __shared__ float red[4];
    int wid = tid >> 6, lane = tid & 63;
    if (lane == 0) red[wid] = acc;
    __syncthreads();
    if (tid == 0) xbar[row] = (red[0] + red[1] + red[2] + red[3]) * (1.0f / NN);
}

// vbar[b*E+e] = Wv[e,:]·xbar[b,:] + bv[e]
// one wave per dot: 1024 dots -> 256 blocks x 4 waves, fully parallel
__global__ void k_vbar(const float* __restrict__ xbar, const float* __restrict__ Wv,
                       const float* __restrict__ bv, float* __restrict__ vbar) {
    int w = threadIdx.x >> 6, lane = threadIdx.x & 63;
    int d = blockIdx.x * 4 + w;        // 0..1023
    int b = d >> 7, e = d & 127;
    const float* wr = Wv + e * CC;
    const float* xb = xbar + b * CC;
    float acc = wr[lane]       * xb[lane]
              + wr[lane + 64]  * xb[lane + 64]
              + wr[lane + 128] * xb[lane + 128]
              + wr[lane + 192] * xb[lane + 192];
    acc = waveReduceSum(acc);
    if (lane == 0) vbar[d] = acc + bv[e];
}

// blocks 0..511: gexp[b*C+c] = Wexp[c,:]·vbar[b,:]   (NO bexp)
// block 512:     A[c] = sum_e Wcat[e]*Wq[e,c] + Wcat[E+e]*Wk[e,c]
//                cst  = Wcat[:E]·bq + Wcat[E:]·bk
__global__ void k_gexp(const float* __restrict__ vbar, const float* __restrict__ Wexp,
                       const float* __restrict__ Wq, const float* __restrict__ bq,
                       const float* __restrict__ Wk, const float* __restrict__ bk,
                       const float* __restrict__ Wcat,
                       float* __restrict__ gexp, float* __restrict__ Aout,
                       float* __restrict__ cst) {
    int tid = threadIdx.x;
    if (blockIdx.x == 512) {
        float a = 0.f;
        #pragma unroll 8
        for (int e = 0; e < EE; e++)
            a += Wcat[e] * Wq[e * CC + tid] + Wcat[EE + e] * Wk[e * CC + tid];
        Aout[tid] = a;
        if (tid < 64) {
            float cp = Wcat[tid] * bq[tid] + Wcat[tid + 64] * bq[tid + 64]
                     + Wcat[EE + tid] * bk[tid] + Wcat[EE + tid + 64] * bk[tid + 64];
            cp = waveReduceSum(cp);
            if (tid == 0) cst[0] = cp;
        }
        return;
    }
    int w = tid >> 6, lane = tid & 63;
    int d = blockIdx.x * 4 + w;        // 0..2047
    int b = d >> 8, c = d & 255;
    const float* we = Wexp + c * EE;
    const float* vb = vbar + b * EE;
    float acc = we[lane] * vb[lane] + we[lane + 64] * vb[lane + 64];
    acc = waveReduceSum(acc);
    if (lane == 0) gexp[d] = acc;
}

// fused s + out. block = (b, tile of 16 float4 = 64 spatial positions)
// phase A: s[i] = relu(sum_c A[c]*x[b,c,i] + cst)
// phase B: out[b,c,i] = x[b,c,i] + s[i]*gexp[b,c] + bexp[c]
__global__ void __launch_bounds__(256) k_fused(
        const float* __restrict__ x, const float* __restrict__ A,
        const float* __restrict__ cst, const float* __restrict__ gexp,
        const float* __restrict__ bexp, float* __restrict__ out) {
    int b = blockIdx.x / NTILES;
    int tile = blockIdx.x - b * NTILES;
    int tid = threadIdx.x;
    int i4l = tid & 15, cg = tid >> 4;   // 16 i-slots x 16 c-groups

    __shared__ float A_s[CC];
    __shared__ float g_s[CC];
    __shared__ float be_s[CC];
    __shared__ float4 part[16][16];
    __shared__ float4 s_s[16];

    A_s[tid]  = A[tid];
    g_s[tid]  = gexp[b * CC + tid];
    be_s[tid] = bexp[tid];
    __syncthreads();

    const float4* x4 = (const float4*)x + (size_t)b * CC * NN4 + tile * T4;
    float4*       o4 = (float4*)out     + (size_t)b * CC * NN4 + tile * T4;

    // phase A: partial c-sum over this thread's 16 channels
    float4 acc = make_float4(0.f, 0.f, 0.f, 0.f);
    #pragma unroll
    for (int j = 0; j < 16; j++) {
        int c = cg * 16 + j;
        float a = A_s[c];
        float4 v = x4[(size_t)c * NN4 + i4l];
        acc.x = fmaf(a, v.x, acc.x);
        acc.y = fmaf(a, v.y, acc.y);
        acc.z = fmaf(a, v.z, acc.z);
        acc.w = fmaf(a, v.w, acc.w);
    }
    part[cg][i4l] = acc;
    __syncthreads();
    if (tid < 16) {
        float4 sum = part[0][tid];
        #pragma unroll
        for (int g = 1; g < 16; g++) {
            float4 p = part[g][tid];
            sum.x += p.x; sum.y += p.y; sum.z += p.z; sum.w += p.w;
        }
        float cv = cst[0];
        float4 s;
        s.x = fmaxf(sum.x + cv, 0.f);
        s.y = fmaxf(sum.y + cv, 0.f);
        s.z = fmaxf(sum.z + cv, 0.f);
        s.w = fmaxf(sum.w + cv, 0.f);
        s_s[tid] = s;
    }
    __syncthreads();

    // phase B: stream all 256 channels of this i-tile (x re-read hits L1/L2)
    float4 sv = s_s[i4l];
    #pragma unroll
    for (int j = 0; j < 16; j++) {
        int c = j * 16 + cg;
        float g  = g_s[c];
        float be = be_s[c];
        size_t off = (size_t)c * NN4 + i4l;
        float4 xv = x4[off];
        float4 o;
        o.x = fmaf(sv.x, g, xv.x) + be;
        o.y = fmaf(sv.y, g, xv.y) + be;
        o.z = fmaf(sv.z, g, xv.z) + be;
        o.w = fmaf(sv.w, g, xv.w) + be;
        o4[off] = o;
    }
}

extern "C" void kernel_launch(void* const* d_in, const int* in_sizes, int n_in,
                              void* d_out, int out_size, void* d_ws, size_t ws_size,
                              hipStream_t stream) {
    const float* x    = (const float*)d_in[0];
    const float* Wq   = (const float*)d_in[1];
    const float* bq   = (const float*)d_in[2];
    const float* Wk   = (const float*)d_in[3];
    const float* bk   = (const float*)d_in[4];
    const float* Wv   = (const float*)d_in[5];
    const float* bv   = (const float*)d_in[6];
    const float* Wcat = (const float*)d_in[7];
    const float* Wexp = (const float*)d_in[8];
    const float* bexp = (const float*)d_in[9];
    float* out = (float*)d_out;

    float* ws   = (float*)d_ws;
    float* xbar = ws;                 // 2048
    float* gexp = ws + 2048;          // 2048
    float* A    = ws + 4096;          // 256
    float* cst  = ws + 4352;          // 1 (+pad)
    float* vbar = ws + 4368;          // 1024

    k_xbar<<<BB * CC, 256, 0, stream>>>(x, xbar);
    k_vbar<<<256, 256, 0, stream>>>(xbar, Wv, bv, vbar);
    k_gexp<<<513, 256, 0, stream>>>(vbar, Wexp, Wq, bq, Wk, bk, Wcat, gexp, A, cst);
    k_fused<<<BB * NTILES, 256, 0, stream>>>(x, A, cst, gexp, bexp, out);
}

// Round 4
// 111.747 us; speedup vs baseline: 1.3673x; 1.0153x over previous
//
#include <hip/hip_runtime.h>

#define CC 256
#define EE 128
#define BB 8
#define NN 3136
#define NN4 784      // NN / 4 (float4 per row)
#define T4 8         // float4 per i-tile (32 spatial positions)
#define NTILES 98    // NN4 / T4

__device__ __forceinline__ float waveReduceSum(float v) {
    #pragma unroll
    for (int off = 32; off > 0; off >>= 1) v += __shfl_down(v, off, 64);
    return v;
}

// xbar[b*C+c] = mean_i x[b,c,i]
__global__ void k_xbar(const float* __restrict__ x, float* __restrict__ xbar) {
    int row = blockIdx.x;          // b*C + c
    int tid = threadIdx.x;
    const float4* xr = (const float4*)(x + (size_t)row * NN);
    float acc = 0.f;
    for (int i = tid; i < NN4; i += 256) {
        float4 v = xr[i];
        acc += (v.x + v.y) + (v.z + v.w);
    }
    acc = waveReduceSum(acc);
    __shared__ float red[4];
    int wid = tid >> 6, lane = tid & 63;
    if (lane == 0) red[wid] = acc;
    __syncthreads();
    if (tid == 0) xbar[row] = (red[0] + red[1] + red[2] + red[3]) * (1.0f / NN);
}

// vbar[b*E+e] = Wv[e,:]·xbar[b,:] + bv[e]
// one wave per dot: 1024 dots -> 256 blocks x 4 waves, fully parallel
__global__ void k_vbar(const float* __restrict__ xbar, const float* __restrict__ Wv,
                       const float* __restrict__ bv, float* __restrict__ vbar) {
    int w = threadIdx.x >> 6, lane = threadIdx.x & 63;
    int d = blockIdx.x * 4 + w;        // 0..1023
    int b = d >> 7, e = d & 127;
    const float* wr = Wv + e * CC;
    const float* xb = xbar + b * CC;
    float acc = wr[lane]       * xb[lane]
              + wr[lane + 64]  * xb[lane + 64]
              + wr[lane + 128] * xb[lane + 128]
              + wr[lane + 192] * xb[lane + 192];
    acc = waveReduceSum(acc);
    if (lane == 0) vbar[d] = acc + bv[e];
}

// blocks 0..511: gexp[b*C+c] = Wexp[c,:]·vbar[b,:]   (NO bexp)
// block 512:     A[c] = sum_e Wcat[e]*Wq[e,c] + Wcat[E+e]*Wk[e,c]
//                cst  = Wcat[:E]·bq + Wcat[E:]·bk
__global__ void k_gexp(const float* __restrict__ vbar, const float* __restrict__ Wexp,
                       const float* __restrict__ Wq, const float* __restrict__ bq,
                       const float* __restrict__ Wk, const float* __restrict__ bk,
                       const float* __restrict__ Wcat,
                       float* __restrict__ gexp, float* __restrict__ Aout,
                       float* __restrict__ cst) {
    int tid = threadIdx.x;
    if (blockIdx.x == 512) {
        float a = 0.f;
        #pragma unroll 8
        for (int e = 0; e < EE; e++)
            a += Wcat[e] * Wq[e * CC + tid] + Wcat[EE + e] * Wk[e * CC + tid];
        Aout[tid] = a;
        if (tid < 64) {
            float cp = Wcat[tid] * bq[tid] + Wcat[tid + 64] * bq[tid + 64]
                     + Wcat[EE + tid] * bk[tid] + Wcat[EE + tid + 64] * bk[tid + 64];
            cp = waveReduceSum(cp);
            if (tid == 0) cst[0] = cp;
        }
        return;
    }
    int w = tid >> 6, lane = tid & 63;
    int d = blockIdx.x * 4 + w;        // 0..2047
    int b = d >> 8, c = d & 255;
    const float* we = Wexp + c * EE;
    const float* vb = vbar + b * EE;
    float acc = we[lane] * vb[lane] + we[lane + 64] * vb[lane + 64];
    acc = waveReduceSum(acc);
    if (lane == 0) gexp[d] = acc;
}

// fused s + out. block = (b, tile of 8 float4 = 32 spatial positions)
// Each thread owns channels c = cg*8 .. cg*8+7 at spatial slot i4l and caches
// its 8 float4 x values in registers between the two phases (x read ONCE).
// phase A: s[i] = relu(sum_c A[c]*x[b,c,i] + cst)
// phase B: out[b,c,i] = x[b,c,i] + s[i]*gexp[b,c] + bexp[c]
__global__ void __launch_bounds__(256) k_fused(
        const float* __restrict__ x, const float* __restrict__ A,
        const float* __restrict__ cst, const float* __restrict__ gexp,
        const float* __restrict__ bexp, float* __restrict__ out) {
    int b = blockIdx.x / NTILES;
    int tile = blockIdx.x - b * NTILES;
    int tid = threadIdx.x;
    int i4l = tid & 7, cg = tid >> 3;   // 8 i-slots x 32 c-groups (8 ch each)

    __shared__ float A_s[CC];
    __shared__ float g_s[CC];
    __shared__ float be_s[CC];
    __shared__ float4 part[32][8];
    __shared__ float4 s_s[8];

    A_s[tid]  = A[tid];
    g_s[tid]  = gexp[b * CC + tid];
    be_s[tid] = bexp[tid];
    __syncthreads();

    const float4* x4 = (const float4*)x + (size_t)b * CC * NN4 + tile * T4;
    float4*       o4 = (float4*)out     + (size_t)b * CC * NN4 + tile * T4;

    // phase A: load this thread's 8 channels once, keep in registers
    float4 xc[8];
    float4 acc = make_float4(0.f, 0.f, 0.f, 0.f);
    #pragma unroll
    for (int j = 0; j < 8; j++) {
        int c = cg * 8 + j;
        float4 v = x4[(size_t)c * NN4 + i4l];
        xc[j] = v;
        float a = A_s[c];
        acc.x = fmaf(a, v.x, acc.x);
        acc.y = fmaf(a, v.y, acc.y);
        acc.z = fmaf(a, v.z, acc.z);
        acc.w = fmaf(a, v.w, acc.w);
    }
    part[cg][i4l] = acc;
    __syncthreads();
    if (tid < 8) {
        float4 sum = part[0][tid];
        #pragma unroll
        for (int g = 1; g < 32; g++) {
            float4 p = part[g][tid];
            sum.x += p.x; sum.y += p.y; sum.z += p.z; sum.w += p.w;
        }
        float cv = cst[0];
        float4 s;
        s.x = fmaxf(sum.x + cv, 0.f);
        s.y = fmaxf(sum.y + cv, 0.f);
        s.z = fmaxf(sum.z + cv, 0.f);
        s.w = fmaxf(sum.w + cv, 0.f);
        s_s[tid] = s;
    }
    __syncthreads();

    // phase B: same channels, x from registers, coalesced stores
    float4 sv = s_s[i4l];
    #pragma unroll
    for (int j = 0; j < 8; j++) {
        int c = cg * 8 + j;
        float g  = g_s[c];
        float be = be_s[c];
        float4 xv = xc[j];
        float4 o;
        o.x = fmaf(sv.x, g, xv.x) + be;
        o.y = fmaf(sv.y, g, xv.y) + be;
        o.z = fmaf(sv.z, g, xv.z) + be;
        o.w = fmaf(sv.w, g, xv.w) + be;
        o4[(size_t)c * NN4 + i4l] = o;
    }
}

extern "C" void kernel_launch(void* const* d_in, const int* in_sizes, int n_in,
                              void* d_out, int out_size, void* d_ws, size_t ws_size,
                              hipStream_t stream) {
    const float* x    = (const float*)d_in[0];
    const float* Wq   = (const float*)d_in[1];
    const float* bq   = (const float*)d_in[2];
    const float* Wk   = (const float*)d_in[3];
    const float* bk   = (const float*)d_in[4];
    const float* Wv   = (const float*)d_in[5];
    const float* bv   = (const float*)d_in[6];
    const float* Wcat = (const float*)d_in[7];
    const float* Wexp = (const float*)d_in[8];
    const float* bexp = (const float*)d_in[9];
    float* out = (float*)d_out;

    float* ws   = (float*)d_ws;
    float* xbar = ws;                 // 2048
    float* gexp = ws + 2048;          // 2048
    float* A    = ws + 4096;          // 256
    float* cst  = ws + 4352;          // 1 (+pad)
    float* vbar = ws + 4368;          // 1024

    k_xbar<<<BB * CC, 256, 0, stream>>>(x, xbar);
    k_vbar<<<256, 256, 0, stream>>>(xbar, Wv, bv, vbar);
    k_gexp<<<513, 256, 0, stream>>>(vbar, Wexp, Wq, bq, Wk, bk, Wcat, gexp, A, cst);
    k_fused<<<BB * NTILES, 256, 0, stream>>>(x, A, cst, gexp, bexp, out);
}